// Round 4
// baseline (1840.408 us; speedup 1.0000x reference)
//
#include <hip/hip_runtime.h>
#include <hip/hip_bf16.h>
#include <stdint.h>

#define C_DIM 128
#define K_DIM 27

typedef __attribute__((ext_vector_type(8))) short short8;
typedef __attribute__((ext_vector_type(4))) float f32x4;
typedef __attribute__((ext_vector_type(4))) unsigned short ushort4v;

#define FENCE() asm volatile("" ::: "memory")
#define VMCNT20() asm volatile("s_waitcnt vmcnt(20)" ::: "memory")
#define LGKM0() asm volatile("s_waitcnt lgkmcnt(0)" ::: "memory")
#define BAR() __builtin_amdgcn_s_barrier()

__device__ __forceinline__ unsigned short f2bf(float f) {
  unsigned int u = __builtin_bit_cast(unsigned int, f);
  u += 0x7fffu + ((u >> 16) & 1u);   // round-to-nearest-even
  return (unsigned short)(u >> 16);
}
__device__ __forceinline__ float bf2f(unsigned short h) {
  unsigned int u = ((unsigned int)h) << 16;
  return __builtin_bit_cast(float, u);
}

__device__ __forceinline__ void async_copy16(const void* gsrc, void* ldst) {
  __builtin_amdgcn_global_load_lds(
      (const __attribute__((address_space(1))) unsigned int*)gsrc,
      (__attribute__((address_space(3))) unsigned int*)ldst, 16, 0, 0);
}

// ---- W [k][ci][co] f32 -> swizzled bf16 [k][co][granule g^(co&7)][8]; zero stats ----
__global__ __launch_bounds__(256) void prep_kernel(
    const float* __restrict__ W1, const float* __restrict__ W2,
    unsigned short* __restrict__ Wt1, unsigned short* __restrict__ Wt2,
    float* __restrict__ stats, int stats_n) {
  int idx = blockIdx.x * 256 + threadIdx.x;
  const int total = K_DIM * C_DIM * C_DIM;
  if (idx < total) {
    int k = idx >> 14;
    int r = idx & 16383;
    int co = r >> 7;
    int gpos = (r >> 3) & 15;
    int e = r & 7;
    int gg = gpos ^ (co & 7);     // logical granule
    int ci = gg * 8 + e;
    int src = (k * C_DIM + ci) * C_DIM + co;
    Wt1[idx] = f2bf(W1[src]);
    Wt2[idx] = f2bf(W2[src]);
  }
  if (idx < stats_n) stats[idx] = 0.f;
}

// ---- x f32 -> bf16 copy ----
__global__ __launch_bounds__(256) void cvt_x_kernel(
    const float* __restrict__ x, unsigned short* __restrict__ xb, int total4) {
  int i = blockIdx.x * 256 + threadIdx.x;
  if (i >= total4) return;
  f32x4 v = ((const f32x4*)x)[i];
  ushort4v u;
#pragma unroll
  for (int j = 0; j < 4; ++j) u[j] = f2bf(v[j]);
  ((ushort4v*)xb)[i] = u;
}

// ---- helpers for the conv kernel ----
__device__ __forceinline__ void stage_w(const unsigned short* Wt_k,
                                        unsigned short* buf, int wave, int lane) {
  const unsigned short* src = Wt_k + wave * 4096 + lane * 8;
  unsigned short* dst = buf + wave * 4096;      // wave-uniform; HW adds lane*16B
#pragma unroll
  for (int c = 0; c < 8; ++c)
    async_copy16(src + c * 512, dst + c * 512);
}

__device__ __forceinline__ void load_idx(int (&idx)[4], const int* __restrict__ nbr,
                                         const int (&nb_off)[4], int k) {
#pragma unroll
  for (int rt = 0; rt < 4; ++rt) idx[rt] = nbr[nb_off[rt] + k];
}

__device__ __forceinline__ void load_a(short8 (&a)[4][4], const int (&idx)[4],
                                       const unsigned short* __restrict__ xb, int lg) {
#pragma unroll
  for (int rt = 0; rt < 4; ++rt) {
    const unsigned short* p = xb + (size_t)idx[rt] * C_DIM + lg * 8;
#pragma unroll
    for (int cs = 0; cs < 4; ++cs)
      a[rt][cs] = *(const short8*)(p + cs * 32);
  }
}

__device__ __forceinline__ void compute_k(
    const unsigned short* wb, short8 (&a)[4][4], f32x4 (&acc)[4][4],
    int lr, int lg, int cg) {
  __builtin_amdgcn_s_setprio(1);
#pragma unroll
  for (int cs = 0; cs < 4; ++cs) {
#pragma unroll
    for (int ct = 0; ct < 4; ++ct) {
      const int co = cg * 64 + ct * 16 + lr;
      const int gg = cs * 4 + lg;
      short8 b = *(const short8*)(wb + co * 128 + ((gg ^ (co & 7)) << 3));
#pragma unroll
      for (int rt = 0; rt < 4; ++rt)
        acc[rt][ct] = __builtin_amdgcn_mfma_f32_16x16x32_bf16(a[rt][cs], b, acc[rt][ct], 0, 0, 0);
    }
  }
  __builtin_amdgcn_s_setprio(0);
}

// ---- gathered GEMM: out[i] = sum_k src[nbr[i,k]] @ W[k], fused BN stats ----
// 256 thr (4 waves), block 128x128; wave (rg,cg) owns 64x64.
// T3/T4 pipeline: counted vmcnt (never 0) across raw s_barrier.
// Queue invariant entering each barrier: stage(8) drained, A_next(16)+I(4)=20 in flight.
template<int OUT_IS_F32>
__global__ __launch_bounds__(256, 2) void conv_kernel(
    const unsigned short* __restrict__ xb, const int* __restrict__ nbr,
    const unsigned short* __restrict__ Wt, void* __restrict__ out_v,
    float* __restrict__ stats, int N) {
  __shared__ __align__(16) unsigned short wbuf[2][16384];  // 2 x 32KB (reused as C-tile)
  __shared__ float s_sum[C_DIM], s_ssum[C_DIM];

  const int tid = threadIdx.x;
  const int wave = tid >> 6, lane = tid & 63;
  const int lr = lane & 15, lg = lane >> 4;
  const int rg = wave >> 1, cg = wave & 1;
  const int row0 = blockIdx.x * 128;

  if (tid < C_DIM) { s_sum[tid] = 0.f; s_ssum[tid] = 0.f; }

  int nb_off[4];
#pragma unroll
  for (int rt = 0; rt < 4; ++rt) {
    int rr = row0 + rg * 64 + rt * 16 + lr;
    nb_off[rt] = (rr < N ? rr : N - 1) * K_DIM;
  }

  // ---- prologue: queue becomes [S0(8), A0(16), I1(4)] ----
  int idxC[4], idxN[4];
  load_idx(idxC, nbr, nb_off, 0);
  FENCE();
  stage_w(Wt, wbuf[0], wave, lane);
  FENCE();
  short8 a0[4][4], a1[4][4];
  load_a(a0, idxC, xb, lg);        // auto-wait drains I0; S0 stays in flight
  FENCE();
  load_idx(idxN, nbr, nb_off, 1);
  LGKM0();                          // s_sum init visible across barrier
  VMCNT20();                        // S0 done; A0+I1 = 20 in flight
  BAR();

  f32x4 acc[4][4] = {};

#define HALF(kk, bufC, bufN, aC, aN)                                    \
  do {                                                                  \
    if ((kk) + 1 < K_DIM) {                                             \
      stage_w(Wt + (size_t)((kk) + 1) * 16384, bufN, wave, lane);       \
      FENCE();                                                          \
      load_a(aN, idxN, xb, lg);  /* auto-wait drains A_cur + I */       \
      FENCE();                                                          \
    }                                                                   \
    { int kk2 = ((kk) + 2 < K_DIM) ? (kk) + 2 : K_DIM - 1;              \
      load_idx(idxN, nbr, nb_off, kk2); }                               \
    FENCE();                                                            \
    compute_k(bufC, aC, acc, lr, lg, cg);                               \
    LGKM0();   /* ds_reads retired before buffer can be re-staged */    \
    VMCNT20(); /* stage done; A_next+I = 20 stay in flight */           \
    BAR();                                                              \
  } while (0)

  for (int k = 0; k < K_DIM; k += 2) {
    HALF(k, wbuf[0], wbuf[1], a0, a1);
    if (k + 1 >= K_DIM) break;
    HALF(k + 1, wbuf[1], wbuf[0], a1, a0);
  }
#undef HALF

  // ---- epilogue: acc -> LDS C-tile -> coalesced stores; fused BN stats ----
  __syncthreads();   // full drain; wbuf safe to reuse
  float* ctile = (float*)wbuf;     // 128 x 128 f32 = 64 KB

  const int wrow_l = rg * 64;
  float ps[4] = {0.f, 0.f, 0.f, 0.f}, pss[4] = {0.f, 0.f, 0.f, 0.f};
#pragma unroll
  for (int rt = 0; rt < 4; ++rt) {
#pragma unroll
    for (int j = 0; j < 4; ++j) {
      int lrow = wrow_l + rt * 16 + lg * 4 + j;
      bool ok = (row0 + lrow) < N;
#pragma unroll
      for (int ct = 0; ct < 4; ++ct) {
        float v = acc[rt][ct][j];
        ctile[lrow * 128 + cg * 64 + ct * 16 + lr] = v;
        if (ok) { ps[ct] += v; pss[ct] += v * v; }
      }
    }
  }
#pragma unroll
  for (int ct = 0; ct < 4; ++ct) {
    ps[ct]  += __shfl_xor(ps[ct], 16, 64);
    ps[ct]  += __shfl_xor(ps[ct], 32, 64);
    pss[ct] += __shfl_xor(pss[ct], 16, 64);
    pss[ct] += __shfl_xor(pss[ct], 32, 64);
    if (lg == 0) {
      int col = cg * 64 + ct * 16 + lr;
      atomicAdd(&s_sum[col], ps[ct]);
      atomicAdd(&s_ssum[col], pss[ct]);
    }
  }
  __syncthreads();
  if (tid < C_DIM) {
    atomicAdd(&stats[tid], s_sum[tid]);
    atomicAdd(&stats[C_DIM + tid], s_ssum[tid]);
  }
  // coalesced writeback: 4096 f32x4 chunks, 16 per thread
  for (int i = tid; i < 4096; i += 256) {
    int row = i >> 5;          // 32 chunks per row
    int c4 = i & 31;
    int grow = row0 + row;
    if (grow >= N) continue;
    f32x4 v = ((const f32x4*)ctile)[i];
    if (OUT_IS_F32) {
      ((f32x4*)out_v)[(size_t)grow * 32 + c4] = v;
    } else {
      ushort4v u;
#pragma unroll
      for (int j = 0; j < 4; ++j) u[j] = f2bf(v[j]);
      ((ushort4v*)out_v)[(size_t)grow * 32 + c4] = u;
    }
  }
}

// ---- stats -> scale/shift ----
__global__ void finalize_kernel(const float* __restrict__ stats,
                                const float* __restrict__ g,
                                const float* __restrict__ b,
                                float* __restrict__ sshift, float invN) {
  int c = threadIdx.x;  // blockDim = 128
  float mean = stats[c] * invN;
  float var = stats[128 + c] * invN - mean * mean;
  float sc = g[c] * rsqrtf(var + 1e-5f);
  sshift[c] = sc;
  sshift[128 + c] = b[c] - mean * sc;
}

// ---- y1 <- relu(bn(y1)) in place, bf16 ----
__global__ __launch_bounds__(256) void apply_kernel(
    unsigned short* __restrict__ y, const float* __restrict__ ss, int total8) {
  int i = blockIdx.x * 256 + threadIdx.x;
  if (i >= total8) return;
  int cb = (i * 8) & 127;
  short8 u = ((short8*)y)[i];
#pragma unroll
  for (int j = 0; j < 8; ++j) {
    float f = bf2f((unsigned short)u[j]) * ss[cb + j] + ss[128 + cb + j];
    u[j] = (short)f2bf(fmaxf(f, 0.f));
  }
  ((short8*)y)[i] = u;
}

// ---- out <- relu(bn(y2) + x) in place (f32) ----
__global__ __launch_bounds__(256) void final_kernel(
    float* __restrict__ y2, const float* __restrict__ x,
    const float* __restrict__ ss, int total4) {
  int i = blockIdx.x * 256 + threadIdx.x;
  if (i >= total4) return;
  int cb = (i * 4) & 127;
  f32x4 v = ((const f32x4*)y2)[i];
  f32x4 xv = ((const f32x4*)x)[i];
#pragma unroll
  for (int j = 0; j < 4; ++j)
    v[j] = fmaxf(v[j] * ss[cb + j] + ss[128 + cb + j] + xv[j], 0.f);
  ((f32x4*)y2)[i] = v;
}

extern "C" void kernel_launch(void* const* d_in, const int* in_sizes, int n_in,
                              void* d_out, int out_size, void* d_ws, size_t ws_size,
                              hipStream_t stream) {
  const float* x  = (const float*)d_in[0];
  const int* nbr  = (const int*)d_in[1];
  const float* W1 = (const float*)d_in[2];
  const float* g1 = (const float*)d_in[3];
  const float* b1 = (const float*)d_in[4];
  const float* W2 = (const float*)d_in[5];
  const float* g2 = (const float*)d_in[6];
  const float* b2 = (const float*)d_in[7];
  float* out = (float*)d_out;

  const int N = in_sizes[0] / C_DIM;
  const int totalW = K_DIM * C_DIM * C_DIM;

  char* ws = (char*)d_ws;
  size_t off = 0;
  auto alloc = [&](size_t bytes) {
    void* p = ws + off;
    off = (off + bytes + 255) & ~(size_t)255;
    return p;
  };
  unsigned short* Wt1 = (unsigned short*)alloc((size_t)totalW * 2);
  unsigned short* Wt2 = (unsigned short*)alloc((size_t)totalW * 2);
  float* stats = (float*)alloc(512 * 4);   // [0:256) conv1, [256:512) conv2
  float* ss1   = (float*)alloc(256 * 4);
  float* ss2   = (float*)alloc(256 * 4);
  unsigned short* y1 = (unsigned short*)alloc((size_t)N * C_DIM * 2);
  unsigned short* xb_ws = (unsigned short*)alloc((size_t)N * C_DIM * 2);
  // fall back to d_out's storage for the bf16 x copy if ws is too small
  unsigned short* xb = (off <= ws_size) ? xb_ws : (unsigned short*)d_out;

  const int nblk = (N + 127) / 128;
  const float invN = 1.0f / (float)N;

  prep_kernel<<<(totalW + 255) / 256, 256, 0, stream>>>(W1, W2, Wt1, Wt2, stats, 512);

  {
    int t4 = N * C_DIM / 4;
    cvt_x_kernel<<<(t4 + 255) / 256, 256, 0, stream>>>(x, xb, t4);
  }

  conv_kernel<0><<<nblk, 256, 0, stream>>>(xb, nbr, Wt1, y1, stats, N);
  finalize_kernel<<<1, 128, 0, stream>>>(stats, g1, b1, ss1, invN);

  {
    int t8 = N * C_DIM / 8;
    apply_kernel<<<(t8 + 255) / 256, 256, 0, stream>>>(y1, ss1, t8);
  }

  conv_kernel<1><<<nblk, 256, 0, stream>>>(y1, nbr, Wt2, out, stats + 256, N);
  finalize_kernel<<<1, 128, 0, stream>>>(stats + 256, g2, b2, ss2, invN);

  {
    int t4 = N * C_DIM / 4;
    final_kernel<<<(t4 + 255) / 256, 256, 0, stream>>>(out, x, ss2, t4);
  }
}

// Round 5
// 666.270 us; speedup vs baseline: 2.7623x; 2.7623x over previous
//
#include <hip/hip_runtime.h>
#include <hip/hip_bf16.h>
#include <stdint.h>

#define C_DIM 128
#define K_DIM 27

typedef __attribute__((ext_vector_type(8))) short short8;
typedef __attribute__((ext_vector_type(4))) float f32x4;
typedef __attribute__((ext_vector_type(4))) unsigned short ushort4v;

#define FENCE() asm volatile("" ::: "memory")
#define VMCNT0() asm volatile("s_waitcnt vmcnt(0)" ::: "memory")
#define LGKM0() asm volatile("s_waitcnt lgkmcnt(0)" ::: "memory")
#define BAR() __builtin_amdgcn_s_barrier()

__device__ __forceinline__ unsigned short f2bf(float f) {
  unsigned int u = __builtin_bit_cast(unsigned int, f);
  u += 0x7fffu + ((u >> 16) & 1u);   // round-to-nearest-even
  return (unsigned short)(u >> 16);
}
__device__ __forceinline__ float bf2f(unsigned short h) {
  unsigned int u = ((unsigned int)h) << 16;
  return __builtin_bit_cast(float, u);
}

__device__ __forceinline__ void async_copy16(const void* gsrc, void* ldst) {
  __builtin_amdgcn_global_load_lds(
      (const __attribute__((address_space(1))) unsigned int*)gsrc,
      (__attribute__((address_space(3))) unsigned int*)ldst, 16, 0, 0);
}

// ---- W [k][ci][co] f32 -> swizzled bf16 [k][co][granule g^(co&7)][8]; zero stats ----
__global__ __launch_bounds__(256) void prep_kernel(
    const float* __restrict__ W1, const float* __restrict__ W2,
    unsigned short* __restrict__ Wt1, unsigned short* __restrict__ Wt2,
    float* __restrict__ stats, int stats_n) {
  int idx = blockIdx.x * 256 + threadIdx.x;
  const int total = K_DIM * C_DIM * C_DIM;
  if (idx < total) {
    int k = idx >> 14;
    int r = idx & 16383;
    int co = r >> 7;
    int gpos = (r >> 3) & 15;
    int e = r & 7;
    int gg = gpos ^ (co & 7);     // logical granule
    int ci = gg * 8 + e;
    int src = (k * C_DIM + ci) * C_DIM + co;
    Wt1[idx] = f2bf(W1[src]);
    Wt2[idx] = f2bf(W2[src]);
  }
  if (idx < stats_n) stats[idx] = 0.f;
}

// ---- x f32 -> bf16 copy ----
__global__ __launch_bounds__(256) void cvt_x_kernel(
    const float* __restrict__ x, unsigned short* __restrict__ xb, int total4) {
  int i = blockIdx.x * 256 + threadIdx.x;
  if (i >= total4) return;
  f32x4 v = ((const f32x4*)x)[i];
  ushort4v u;
#pragma unroll
  for (int j = 0; j < 4; ++j) u[j] = f2bf(v[j]);
  ((ushort4v*)xb)[i] = u;
}

// ---- gathered GEMM: out[i] = sum_k src[nbr[i,k]] @ W[k], fused BN stats ----
// 512 thr (8 waves), block 128 rows x 128 cols; wave (rg=w>>1, cg=w&1) owns 32x64.
// A tile (128x128 bf16, 32KB) gathered into LDS per k via per-lane-source
// global_load_lds (XOR-swizzled source, linear LDS, swizzled ds_read).
// W tile staged likewise from pre-swizzled Wt. Both double-buffered.
template<int OUT_IS_F32>
__global__ __launch_bounds__(512, 1) void conv_kernel(
    const unsigned short* __restrict__ xb, const int* __restrict__ nbr,
    const unsigned short* __restrict__ Wt, void* __restrict__ out_v,
    float* __restrict__ stats, int N) {
  extern __shared__ __align__(16) char smem[];
  unsigned short* Wbuf = (unsigned short*)smem;              // 2 x 32 KB
  unsigned short* Abuf = (unsigned short*)(smem + 65536);    // 2 x 32 KB (reused as ctile)
  int* idx_lds = (int*)(smem + 131072);                      // 128*27 ints = 13824 B
  float* s_sum = (float*)(smem + 131072 + 13824);            // 128 f32
  float* s_ssum = s_sum + C_DIM;                             // 128 f32

  const int tid = threadIdx.x;
  const int wave = tid >> 6, lane = tid & 63;
  const int lr = lane & 15, lg = lane >> 4;
  const int rg = wave >> 1, cg = wave & 1;
  const int row0 = blockIdx.x * 128;

  if (tid < C_DIM) { s_sum[tid] = 0.f; s_ssum[tid] = 0.f; }

  // preload nbr indices for the block's 128 rows (coalesced), clamp OOB rows
  for (int i = tid; i < 128 * K_DIM; i += 512) {
    int r = i / K_DIM;
    int k = i - r * K_DIM;
    int rr = row0 + r; if (rr >= N) rr = N - 1;
    idx_lds[i] = nbr[(size_t)rr * K_DIM + k];
  }
  __syncthreads();

  // --- staging: wave w covers LDS rows [w*16, w*16+16); issue c covers 4 rows.
  // lane -> row = w*16 + c*4 + lg, granule slot = lr. Source granule = lr ^ (row&7)
  // so that ds_read with the same XOR is 2-way-conflict-free.
  auto stage_a = [&](const int (&gi)[4], int buf) {
    unsigned short* dstb = Abuf + buf * 16384 + wave * 2048;
#pragma unroll
    for (int c = 0; c < 4; ++c) {
      const int rloc = wave * 16 + c * 4 + lg;
      const unsigned short* src =
          xb + (size_t)gi[c] * C_DIM + ((lr ^ (rloc & 7)) << 3);
      async_copy16(src, dstb + c * 512);
    }
  };
  auto stage_w = [&](int k, int buf) {
    const unsigned short* src = Wt + (size_t)k * 16384 + wave * 2048 + lane * 8;
    unsigned short* dstb = Wbuf + buf * 16384 + wave * 2048;
#pragma unroll
    for (int c = 0; c < 4; ++c)
      async_copy16(src + c * 512, dstb + c * 512);
  };
  auto read_gi = [&](int k, int (&gi)[4]) {
#pragma unroll
    for (int c = 0; c < 4; ++c)
      gi[c] = idx_lds[(wave * 16 + c * 4 + lg) * K_DIM + k];
  };

  // ---- prologue: stage k=0, prefetch gi for k=1 ----
  int gi[4];
  read_gi(0, gi);
  stage_a(gi, 0);
  stage_w(0, 0);
  read_gi(1, gi);
  f32x4 acc[2][4] = {};
  LGKM0();
  VMCNT0();
  BAR();

  int cur = 0;
  for (int k = 0; k < K_DIM; ++k) {
    if (k + 1 < K_DIM) {           // issue next-tile stages first (T14)
      stage_a(gi, cur ^ 1);
      stage_w(k + 1, cur ^ 1);
    }
    FENCE();
    { int kn = (k + 2 < K_DIM) ? k + 2 : K_DIM - 1; read_gi(kn, gi); }
    FENCE();
    // ---- compute k from buf[cur] ----
    const unsigned short* wb = Wbuf + cur * 16384;
    const unsigned short* ab = Abuf + cur * 16384;
    __builtin_amdgcn_s_setprio(1);
#pragma unroll
    for (int cs = 0; cs < 4; ++cs) {
      const int gq = cs * 4 + lg;
      const int sw = (gq ^ (lr & 7)) << 3;
      short8 a0 = *(const short8*)(ab + (rg * 32 + lr) * C_DIM + sw);
      short8 a1 = *(const short8*)(ab + (rg * 32 + 16 + lr) * C_DIM + sw);
#pragma unroll
      for (int ct = 0; ct < 4; ++ct) {
        const int co = cg * 64 + ct * 16 + lr;
        short8 b = *(const short8*)(wb + co * C_DIM + ((gq ^ (co & 7)) << 3));
        acc[0][ct] = __builtin_amdgcn_mfma_f32_16x16x32_bf16(a0, b, acc[0][ct], 0, 0, 0);
        acc[1][ct] = __builtin_amdgcn_mfma_f32_16x16x32_bf16(a1, b, acc[1][ct], 0, 0, 0);
      }
    }
    __builtin_amdgcn_s_setprio(0);
    LGKM0();     // compute's ds_reads + gi reads retired
    VMCNT0();    // stage(k+1) landed in LDS
    BAR();
    cur ^= 1;
  }

  // ---- epilogue: acc -> LDS ctile -> coalesced stores; fused BN stats ----
  float* ctile = (float*)Abuf;     // 128x128 f32 = 64 KB (Abuf region)
  float ps[4] = {0.f, 0.f, 0.f, 0.f}, pss[4] = {0.f, 0.f, 0.f, 0.f};
  const int wr0 = rg * 32;
#pragma unroll
  for (int rt = 0; rt < 2; ++rt) {
#pragma unroll
    for (int j = 0; j < 4; ++j) {
      int lrow = wr0 + rt * 16 + lg * 4 + j;
      bool ok = (row0 + lrow) < N;
#pragma unroll
      for (int ct = 0; ct < 4; ++ct) {
        float v = acc[rt][ct][j];
        ctile[lrow * C_DIM + cg * 64 + ct * 16 + lr] = v;
        if (ok) { ps[ct] += v; pss[ct] += v * v; }
      }
    }
  }
#pragma unroll
  for (int ct = 0; ct < 4; ++ct) {
    ps[ct]  += __shfl_xor(ps[ct], 16, 64);
    ps[ct]  += __shfl_xor(ps[ct], 32, 64);
    pss[ct] += __shfl_xor(pss[ct], 16, 64);
    pss[ct] += __shfl_xor(pss[ct], 32, 64);
    if (lg == 0) {
      int col = cg * 64 + ct * 16 + lr;
      atomicAdd(&s_sum[col], ps[ct]);
      atomicAdd(&s_ssum[col], pss[ct]);
    }
  }
  __syncthreads();
  if (tid < C_DIM) {
    atomicAdd(&stats[tid], s_sum[tid]);
    atomicAdd(&stats[C_DIM + tid], s_ssum[tid]);
  }
  // coalesced writeback: 4096 f32x4 chunks, 8 per thread
  for (int i = tid; i < 4096; i += 512) {
    int row = i >> 5;
    int c4 = i & 31;
    int grow = row0 + row;
    if (grow >= N) continue;
    f32x4 v = ((const f32x4*)ctile)[i];
    if (OUT_IS_F32) {
      ((f32x4*)out_v)[(size_t)grow * 32 + c4] = v;
    } else {
      ushort4v u;
#pragma unroll
      for (int j = 0; j < 4; ++j) u[j] = f2bf(v[j]);
      ((ushort4v*)out_v)[(size_t)grow * 32 + c4] = u;
    }
  }
}

// ---- stats -> scale/shift ----
__global__ void finalize_kernel(const float* __restrict__ stats,
                                const float* __restrict__ g,
                                const float* __restrict__ b,
                                float* __restrict__ sshift, float invN) {
  int c = threadIdx.x;  // blockDim = 128
  float mean = stats[c] * invN;
  float var = stats[128 + c] * invN - mean * mean;
  float sc = g[c] * rsqrtf(var + 1e-5f);
  sshift[c] = sc;
  sshift[128 + c] = b[c] - mean * sc;
}

// ---- y1 <- relu(bn(y1)) in place, bf16 ----
__global__ __launch_bounds__(256) void apply_kernel(
    unsigned short* __restrict__ y, const float* __restrict__ ss, int total8) {
  int i = blockIdx.x * 256 + threadIdx.x;
  if (i >= total8) return;
  int cb = (i * 8) & 127;
  short8 u = ((short8*)y)[i];
#pragma unroll
  for (int j = 0; j < 8; ++j) {
    float f = bf2f((unsigned short)u[j]) * ss[cb + j] + ss[128 + cb + j];
    u[j] = (short)f2bf(fmaxf(f, 0.f));
  }
  ((short8*)y)[i] = u;
}

// ---- out <- relu(bn(y2) + x) in place (f32) ----
__global__ __launch_bounds__(256) void final_kernel(
    float* __restrict__ y2, const float* __restrict__ x,
    const float* __restrict__ ss, int total4) {
  int i = blockIdx.x * 256 + threadIdx.x;
  if (i >= total4) return;
  int cb = (i * 4) & 127;
  f32x4 v = ((const f32x4*)y2)[i];
  f32x4 xv = ((const f32x4*)x)[i];
#pragma unroll
  for (int j = 0; j < 4; ++j)
    v[j] = fmaxf(v[j] * ss[cb + j] + ss[128 + cb + j] + xv[j], 0.f);
  ((f32x4*)y2)[i] = v;
}

extern "C" void kernel_launch(void* const* d_in, const int* in_sizes, int n_in,
                              void* d_out, int out_size, void* d_ws, size_t ws_size,
                              hipStream_t stream) {
  const float* x  = (const float*)d_in[0];
  const int* nbr  = (const int*)d_in[1];
  const float* W1 = (const float*)d_in[2];
  const float* g1 = (const float*)d_in[3];
  const float* b1 = (const float*)d_in[4];
  const float* W2 = (const float*)d_in[5];
  const float* g2 = (const float*)d_in[6];
  const float* b2 = (const float*)d_in[7];
  float* out = (float*)d_out;

  const int N = in_sizes[0] / C_DIM;
  const int totalW = K_DIM * C_DIM * C_DIM;
  const int SMEM_BYTES = 65536 + 65536 + 13824 + 1024;   // 145920

  char* ws = (char*)d_ws;
  size_t off = 0;
  auto alloc = [&](size_t bytes) {
    void* p = ws + off;
    off = (off + bytes + 255) & ~(size_t)255;
    return p;
  };
  unsigned short* Wt1 = (unsigned short*)alloc((size_t)totalW * 2);
  unsigned short* Wt2 = (unsigned short*)alloc((size_t)totalW * 2);
  float* stats = (float*)alloc(512 * 4);   // [0:256) conv1, [256:512) conv2
  float* ss1   = (float*)alloc(256 * 4);
  float* ss2   = (float*)alloc(256 * 4);
  unsigned short* y1 = (unsigned short*)alloc((size_t)N * C_DIM * 2);
  unsigned short* xb_ws = (unsigned short*)alloc((size_t)N * C_DIM * 2);
  // fall back to d_out's storage for the bf16 x copy if ws is too small
  unsigned short* xb = (off <= ws_size) ? xb_ws : (unsigned short*)d_out;

  // allow >64KB dynamic LDS (ignore errors; idempotent, host-side only)
  (void)hipFuncSetAttribute((const void*)conv_kernel<0>,
      hipFuncAttributeMaxDynamicSharedMemorySize, SMEM_BYTES);
  (void)hipFuncSetAttribute((const void*)conv_kernel<1>,
      hipFuncAttributeMaxDynamicSharedMemorySize, SMEM_BYTES);

  const int nblk = (N + 127) / 128;
  const float invN = 1.0f / (float)N;

  prep_kernel<<<(totalW + 255) / 256, 256, 0, stream>>>(W1, W2, Wt1, Wt2, stats, 512);

  {
    int t4 = N * C_DIM / 4;
    cvt_x_kernel<<<(t4 + 255) / 256, 256, 0, stream>>>(x, xb, t4);
  }

  conv_kernel<0><<<nblk, 512, SMEM_BYTES, stream>>>(xb, nbr, Wt1, y1, stats, N);
  finalize_kernel<<<1, 128, 0, stream>>>(stats, g1, b1, ss1, invN);

  {
    int t8 = N * C_DIM / 8;
    apply_kernel<<<(t8 + 255) / 256, 256, 0, stream>>>(y1, ss1, t8);
  }

  conv_kernel<1><<<nblk, 512, SMEM_BYTES, stream>>>(y1, nbr, Wt2, out, stats + 256, N);
  finalize_kernel<<<1, 128, 0, stream>>>(stats + 256, g2, b2, ss2, invN);

  {
    int t4 = N * C_DIM / 4;
    final_kernel<<<(t4 + 255) / 256, 256, 0, stream>>>(out, x, ss2, t4);
  }
}

// Round 6
// 609.037 us; speedup vs baseline: 3.0218x; 1.0940x over previous
//
#include <hip/hip_runtime.h>
#include <hip/hip_bf16.h>
#include <stdint.h>

#define C_DIM 128
#define K_DIM 27

typedef __attribute__((ext_vector_type(8))) short short8;
typedef __attribute__((ext_vector_type(4))) float f32x4;
typedef __attribute__((ext_vector_type(4))) unsigned short ushort4v;

#define FENCE() asm volatile("" ::: "memory")
#define VMCNT0() asm volatile("s_waitcnt vmcnt(0)" ::: "memory")
#define LGKM0() asm volatile("s_waitcnt lgkmcnt(0)" ::: "memory")
#define BAR() __builtin_amdgcn_s_barrier()

__device__ __forceinline__ unsigned short f2bf(float f) {
  unsigned int u = __builtin_bit_cast(unsigned int, f);
  u += 0x7fffu + ((u >> 16) & 1u);   // round-to-nearest-even
  return (unsigned short)(u >> 16);
}
__device__ __forceinline__ float bf2f(unsigned short h) {
  unsigned int u = ((unsigned int)h) << 16;
  return __builtin_bit_cast(float, u);
}

__device__ __forceinline__ void async_copy16(const void* gsrc, void* ldst) {
  __builtin_amdgcn_global_load_lds(
      (const __attribute__((address_space(1))) unsigned int*)gsrc,
      (__attribute__((address_space(3))) unsigned int*)ldst, 16, 0, 0);
}

// ---- W [k][ci][co] f32 -> phase-tiled swizzled bf16
// Wt[k][h][co][slot][e] where logical ci = h*64 + (slot^(co&7))*8 + e.
__global__ __launch_bounds__(256) void prep_kernel(
    const float* __restrict__ W1, const float* __restrict__ W2,
    unsigned short* __restrict__ Wt1, unsigned short* __restrict__ Wt2,
    float* __restrict__ stats, int stats_n) {
  int idx = blockIdx.x * 256 + threadIdx.x;
  const int total = K_DIM * C_DIM * C_DIM;
  if (idx < total) {
    int e = idx & 7;
    int s = (idx >> 3) & 7;
    int co = (idx >> 6) & 127;
    int h = (idx >> 13) & 1;
    int k = idx >> 14;
    int ci = h * 64 + ((s ^ (co & 7)) << 3) + e;
    int src = (k * C_DIM + ci) * C_DIM + co;
    Wt1[idx] = f2bf(W1[src]);
    Wt2[idx] = f2bf(W2[src]);
  }
  if (idx < stats_n) stats[idx] = 0.f;
}

// ---- x f32 -> bf16 copy ----
__global__ __launch_bounds__(256) void cvt_x_kernel(
    const float* __restrict__ x, unsigned short* __restrict__ xb, int total4) {
  int i = blockIdx.x * 256 + threadIdx.x;
  if (i >= total4) return;
  f32x4 v = ((const f32x4*)x)[i];
  ushort4v u;
#pragma unroll
  for (int j = 0; j < 4; ++j) u[j] = f2bf(v[j]);
  ((ushort4v*)xb)[i] = u;
}

// ---- gathered GEMM: out[i] = sum_k src[nbr[i,k]] @ W[k], fused BN stats ----
// 256 thr (4 waves), block 128 rows x 128 cols; wave (rg,cg) owns 64x64.
// 54 half-k phases (k, ci-half h); A and W phase tiles (16 KB each) double-
// buffered in LDS (78.5 KB total -> 2 blocks/CU = 2 independent barrier
// domains). gi register-carried per k, shared by both halves.
template<int OUT_IS_F32>
__global__ __launch_bounds__(256, 2) void conv_kernel(
    const unsigned short* __restrict__ xb, const int* __restrict__ nbr,
    const unsigned short* __restrict__ Wt, void* __restrict__ out_v,
    float* __restrict__ stats, int N) {
  extern __shared__ __align__(16) char smem[];
  unsigned short* Wbuf = (unsigned short*)smem;            // 2 x 8192 elems
  unsigned short* Abuf = (unsigned short*)(smem + 32768);  // 2 x 8192 elems
  int* idx_lds = (int*)(smem + 65536);                     // 128*27 ints
  float* s_sum = (float*)(smem + 65536 + 13824);           // 128 f32
  float* s_ssum = s_sum + C_DIM;                           // 128 f32

  const int tid = threadIdx.x;
  const int wave = tid >> 6, lane = tid & 63;
  const int lr = lane & 15, lg = lane >> 4;
  const int rg = wave >> 1, cg = wave & 1;
  const int row0 = blockIdx.x * 128;

  if (tid < C_DIM) { s_sum[tid] = 0.f; s_ssum[tid] = 0.f; }

  // preload nbr indices for the block's 128 rows (coalesced), clamp OOB rows
  for (int i = tid; i < 128 * K_DIM; i += 256) {
    int r = i / K_DIM;
    int k = i - r * K_DIM;
    int rr = row0 + r; if (rr >= N) rr = N - 1;
    idx_lds[i] = nbr[(size_t)rr * K_DIM + k];
  }
  __syncthreads();

  // staging: wave covers 32 A-rows per phase; instr c covers 8 rows.
  // lane: sub-row sr = lane>>3, granule g = lane&7; LDS stays linear,
  // source granule = g ^ (row&7) so swizzled ds_read is conflict-spread.
  const int sr = lane >> 3, g = lane & 7;

  auto stage_a = [&](const int (&gi)[4], int h, int buf) {
    unsigned short* dst = Abuf + buf * 8192 + wave * 2048;
#pragma unroll
    for (int c = 0; c < 4; ++c) {
      const unsigned short* src =
          xb + (size_t)gi[c] * C_DIM + h * 64 + ((g ^ (sr & 7)) << 3);
      async_copy16(src, dst + c * 512);
    }
  };
  auto stage_w = [&](int p, int buf) {    // p = k*2 + h
    const unsigned short* src = Wt + (size_t)p * 8192 + wave * 2048 + lane * 8;
    unsigned short* dst = Wbuf + buf * 8192 + wave * 2048;
#pragma unroll
    for (int c = 0; c < 4; ++c)
      async_copy16(src + c * 512, dst + c * 512);
  };
  auto read_gi = [&](int k, int (&gi)[4]) {
#pragma unroll
    for (int c = 0; c < 4; ++c)
      gi[c] = idx_lds[(wave * 32 + c * 8 + sr) * K_DIM + k];
  };

  f32x4 acc[4][4] = {};

  auto compute = [&](int buf) {
    const unsigned short* ab = Abuf + buf * 8192;
    const unsigned short* wb = Wbuf + buf * 8192;
    __builtin_amdgcn_s_setprio(1);
#pragma unroll
    for (int cs = 0; cs < 2; ++cs) {
      const int slot = ((cs * 4 + lg) ^ (lr & 7)) << 3;
      short8 a[4], b[4];
#pragma unroll
      for (int rt = 0; rt < 4; ++rt)
        a[rt] = *(const short8*)(ab + (rg * 64 + rt * 16 + lr) * 64 + slot);
#pragma unroll
      for (int ct = 0; ct < 4; ++ct)
        b[ct] = *(const short8*)(wb + (cg * 64 + ct * 16 + lr) * 64 + slot);
#pragma unroll
      for (int rt = 0; rt < 4; ++rt)
#pragma unroll
        for (int ct = 0; ct < 4; ++ct)
          acc[rt][ct] = __builtin_amdgcn_mfma_f32_16x16x32_bf16(a[rt], b[ct], acc[rt][ct], 0, 0, 0);
    }
    __builtin_amdgcn_s_setprio(0);
  };

  // ---- prologue ----
  int giC[4], giN[4];
  read_gi(0, giC);
  LGKM0();                       // giC ready for staging
  stage_a(giC, 0, 0);
  stage_w(0, 0);
  LGKM0();
  VMCNT0();
  BAR();

  const int NP = K_DIM * 2;      // 54 phases
#pragma unroll 2
  for (int p = 0; p < NP; ++p) {
    const int k = p >> 1, h = p & 1, cur = p & 1;
    if (p + 1 < NP) {
      if (h == 0) {
        stage_a(giC, 1, cur ^ 1);        // (k, h=1)
        stage_w(p + 1, cur ^ 1);
        read_gi(k + 1 < K_DIM ? k + 1 : k, giN);
      } else {
        stage_a(giN, 0, cur ^ 1);        // (k+1, h=0)
        stage_w(p + 1, cur ^ 1);
#pragma unroll
        for (int c = 0; c < 4; ++c) giC[c] = giN[c];
      }
    }
    FENCE();
    compute(cur);
    LGKM0();     // own ds_reads (+ gi reads) retired
    VMCNT0();    // stage of next phase landed
    BAR();
  }

  // ---- epilogue: acc -> LDS ctile -> coalesced stores; fused BN stats ----
  float* ctile = (float*)smem;   // 128x128 f32 = 64 KB (Wbuf+Abuf regions)
  float ps[4] = {0.f, 0.f, 0.f, 0.f}, pss[4] = {0.f, 0.f, 0.f, 0.f};
#pragma unroll
  for (int rt = 0; rt < 4; ++rt) {
#pragma unroll
    for (int j = 0; j < 4; ++j) {
      int lrow = rg * 64 + rt * 16 + lg * 4 + j;
      bool ok = (row0 + lrow) < N;
#pragma unroll
      for (int ct = 0; ct < 4; ++ct) {
        float v = acc[rt][ct][j];
        ctile[lrow * C_DIM + cg * 64 + ct * 16 + lr] = v;
        if (ok) { ps[ct] += v; pss[ct] += v * v; }
      }
    }
  }
#pragma unroll
  for (int ct = 0; ct < 4; ++ct) {
    ps[ct]  += __shfl_xor(ps[ct], 16, 64);
    ps[ct]  += __shfl_xor(ps[ct], 32, 64);
    pss[ct] += __shfl_xor(pss[ct], 16, 64);
    pss[ct] += __shfl_xor(pss[ct], 32, 64);
    if (lg == 0) {
      int col = cg * 64 + ct * 16 + lr;
      atomicAdd(&s_sum[col], ps[ct]);
      atomicAdd(&s_ssum[col], pss[ct]);
    }
  }
  __syncthreads();
  if (tid < C_DIM) {
    atomicAdd(&stats[tid], s_sum[tid]);
    atomicAdd(&stats[C_DIM + tid], s_ssum[tid]);
  }
  // coalesced writeback: 4096 f32x4 chunks, 16 per thread
  for (int i = tid; i < 4096; i += 256) {
    int row = i >> 5;
    int c4 = i & 31;
    int grow = row0 + row;
    if (grow >= N) continue;
    f32x4 v = ((const f32x4*)ctile)[i];
    if (OUT_IS_F32) {
      ((f32x4*)out_v)[(size_t)grow * 32 + c4] = v;
    } else {
      ushort4v u;
#pragma unroll
      for (int j = 0; j < 4; ++j) u[j] = f2bf(v[j]);
      ((ushort4v*)out_v)[(size_t)grow * 32 + c4] = u;
    }
  }
}

// ---- stats -> scale/shift ----
__global__ void finalize_kernel(const float* __restrict__ stats,
                                const float* __restrict__ g,
                                const float* __restrict__ b,
                                float* __restrict__ sshift, float invN) {
  int c = threadIdx.x;  // blockDim = 128
  float mean = stats[c] * invN;
  float var = stats[128 + c] * invN - mean * mean;
  float sc = g[c] * rsqrtf(var + 1e-5f);
  sshift[c] = sc;
  sshift[128 + c] = b[c] - mean * sc;
}

// ---- y1 <- relu(bn(y1)) in place, bf16 ----
__global__ __launch_bounds__(256) void apply_kernel(
    unsigned short* __restrict__ y, const float* __restrict__ ss, int total8) {
  int i = blockIdx.x * 256 + threadIdx.x;
  if (i >= total8) return;
  int cb = (i * 8) & 127;
  short8 u = ((short8*)y)[i];
#pragma unroll
  for (int j = 0; j < 8; ++j) {
    float f = bf2f((unsigned short)u[j]) * ss[cb + j] + ss[128 + cb + j];
    u[j] = (short)f2bf(fmaxf(f, 0.f));
  }
  ((short8*)y)[i] = u;
}

// ---- out <- relu(bn(y2) + x) in place (f32) ----
__global__ __launch_bounds__(256) void final_kernel(
    float* __restrict__ y2, const float* __restrict__ x,
    const float* __restrict__ ss, int total4) {
  int i = blockIdx.x * 256 + threadIdx.x;
  if (i >= total4) return;
  int cb = (i * 4) & 127;
  f32x4 v = ((const f32x4*)y2)[i];
  f32x4 xv = ((const f32x4*)x)[i];
#pragma unroll
  for (int j = 0; j < 4; ++j)
    v[j] = fmaxf(v[j] * ss[cb + j] + ss[128 + cb + j] + xv[j], 0.f);
  ((f32x4*)y2)[i] = v;
}

extern "C" void kernel_launch(void* const* d_in, const int* in_sizes, int n_in,
                              void* d_out, int out_size, void* d_ws, size_t ws_size,
                              hipStream_t stream) {
  const float* x  = (const float*)d_in[0];
  const int* nbr  = (const int*)d_in[1];
  const float* W1 = (const float*)d_in[2];
  const float* g1 = (const float*)d_in[3];
  const float* b1 = (const float*)d_in[4];
  const float* W2 = (const float*)d_in[5];
  const float* g2 = (const float*)d_in[6];
  const float* b2 = (const float*)d_in[7];
  float* out = (float*)d_out;

  const int N = in_sizes[0] / C_DIM;
  const int totalW = K_DIM * C_DIM * C_DIM;
  const int SMEM_BYTES = 65536 + 13824 + 1024;   // 80384 (<= 81920 -> 2 blocks/CU)

  char* ws = (char*)d_ws;
  size_t off = 0;
  auto alloc = [&](size_t bytes) {
    void* p = ws + off;
    off = (off + bytes + 255) & ~(size_t)255;
    return p;
  };
  unsigned short* Wt1 = (unsigned short*)alloc((size_t)totalW * 2);
  unsigned short* Wt2 = (unsigned short*)alloc((size_t)totalW * 2);
  float* stats = (float*)alloc(512 * 4);   // [0:256) conv1, [256:512) conv2
  float* ss1   = (float*)alloc(256 * 4);
  float* ss2   = (float*)alloc(256 * 4);
  unsigned short* y1 = (unsigned short*)alloc((size_t)N * C_DIM * 2);
  unsigned short* xb_ws = (unsigned short*)alloc((size_t)N * C_DIM * 2);
  // fall back to d_out's storage for the bf16 x copy if ws is too small
  unsigned short* xb = (off <= ws_size) ? xb_ws : (unsigned short*)d_out;

  (void)hipFuncSetAttribute((const void*)conv_kernel<0>,
      hipFuncAttributeMaxDynamicSharedMemorySize, SMEM_BYTES);
  (void)hipFuncSetAttribute((const void*)conv_kernel<1>,
      hipFuncAttributeMaxDynamicSharedMemorySize, SMEM_BYTES);

  const int nblk = (N + 127) / 128;
  const float invN = 1.0f / (float)N;

  prep_kernel<<<(totalW + 255) / 256, 256, 0, stream>>>(W1, W2, Wt1, Wt2, stats, 512);

  {
    int t4 = N * C_DIM / 4;
    cvt_x_kernel<<<(t4 + 255) / 256, 256, 0, stream>>>(x, xb, t4);
  }

  conv_kernel<0><<<nblk, 256, SMEM_BYTES, stream>>>(xb, nbr, Wt1, y1, stats, N);
  finalize_kernel<<<1, 128, 0, stream>>>(stats, g1, b1, ss1, invN);

  {
    int t8 = N * C_DIM / 8;
    apply_kernel<<<(t8 + 255) / 256, 256, 0, stream>>>(y1, ss1, t8);
  }

  conv_kernel<1><<<nblk, 256, SMEM_BYTES, stream>>>(y1, nbr, Wt2, out, stats + 256, N);
  finalize_kernel<<<1, 128, 0, stream>>>(stats + 256, g2, b2, ss2, invN);

  {
    int t4 = N * C_DIM / 4;
    final_kernel<<<(t4 + 255) / 256, 256, 0, stream>>>(out, x, ss2, t4);
  }
}

// Round 7
// 582.902 us; speedup vs baseline: 3.1573x; 1.0448x over previous
//
#include <hip/hip_runtime.h>
#include <hip/hip_bf16.h>
#include <stdint.h>

#define C_DIM 128
#define K_DIM 27

typedef __attribute__((ext_vector_type(8))) short short8;
typedef __attribute__((ext_vector_type(4))) float f32x4;
typedef __attribute__((ext_vector_type(4))) unsigned short ushort4v;

#define VMCNT8() asm volatile("s_waitcnt vmcnt(8)" ::: "memory")
#define VMCNT4() asm volatile("s_waitcnt vmcnt(4)" ::: "memory")
#define VMCNT0() asm volatile("s_waitcnt vmcnt(0)" ::: "memory")
#define LGKM0() asm volatile("s_waitcnt lgkmcnt(0)" ::: "memory")
#define BAR() __builtin_amdgcn_s_barrier()

__device__ __forceinline__ unsigned short f2bf(float f) {
  unsigned int u = __builtin_bit_cast(unsigned int, f);
  u += 0x7fffu + ((u >> 16) & 1u);   // round-to-nearest-even
  return (unsigned short)(u >> 16);
}
__device__ __forceinline__ float bf2f(unsigned short h) {
  unsigned int u = ((unsigned int)h) << 16;
  return __builtin_bit_cast(float, u);
}

__device__ __forceinline__ void async_copy16(const void* gsrc, void* ldst) {
  __builtin_amdgcn_global_load_lds(
      (const __attribute__((address_space(1))) unsigned int*)gsrc,
      (__attribute__((address_space(3))) unsigned int*)ldst, 16, 0, 0);
}

// ---- W [k][ci][co] f32 -> quarter-tiled bf16 Wt[k][q][co][cq], ci = q*32+cq ----
__global__ __launch_bounds__(256) void prep_kernel(
    const float* __restrict__ W1, const float* __restrict__ W2,
    unsigned short* __restrict__ Wt1, unsigned short* __restrict__ Wt2,
    float* __restrict__ stats, int stats_n) {
  int idx = blockIdx.x * 256 + threadIdx.x;
  const int total = K_DIM * C_DIM * C_DIM;
  if (idx < total) {
    int cq = idx & 31;
    int co = (idx >> 5) & 127;
    int q  = (idx >> 12) & 3;
    int k  = idx >> 14;
    int ci = q * 32 + cq;
    int src = (k * C_DIM + ci) * C_DIM + co;
    Wt1[idx] = f2bf(W1[src]);
    Wt2[idx] = f2bf(W2[src]);
  }
  if (idx < stats_n) stats[idx] = 0.f;
}

// ---- x f32 -> bf16 copy ----
__global__ __launch_bounds__(256) void cvt_x_kernel(
    const float* __restrict__ x, unsigned short* __restrict__ xb, int total4) {
  int i = blockIdx.x * 256 + threadIdx.x;
  if (i >= total4) return;
  f32x4 v = ((const f32x4*)x)[i];
  ushort4v u;
#pragma unroll
  for (int j = 0; j < 4; ++j) u[j] = f2bf(v[j]);
  ((ushort4v*)xb)[i] = u;
}

// ---- gathered GEMM: out[i] = sum_k src[nbr[i,k]] @ W[k], fused BN stats ----
// 256 thr (4 waves), block 128 rows x 128 cols; wave (rg,cg) owns 64x64.
// 108 quarter-k phases; A/W 8KB quarter-tiles in a 4-deep LDS ring buffer,
// lookahead 3, counted vmcnt(8) at each barrier (never 0 in main loop).
// 32-ci rows = 64B -> fragment reads are contiguous 1KB blocks (no conflicts).
template<int OUT_IS_F32>
__global__ __launch_bounds__(256, 2) void conv_kernel(
    const unsigned short* __restrict__ xb, const int* __restrict__ nbr,
    const unsigned short* __restrict__ Wt, void* __restrict__ out_v,
    float* __restrict__ stats, int N) {
  extern __shared__ __align__(16) char smem[];
  unsigned short* Abuf = (unsigned short*)smem;            // 4 x 4096 elems
  unsigned short* Wbuf = (unsigned short*)(smem + 32768);  // 4 x 4096 elems
  int* idx_lds = (int*)(smem + 65536);                     // 128*27 ints
  float* s_sum = (float*)(smem + 65536 + 13824);           // 128 f32
  float* s_ssum = s_sum + C_DIM;                           // 128 f32

  const int tid = threadIdx.x;
  const int wave = tid >> 6, lane = tid & 63;
  const int lr = lane & 15, lg = lane >> 4;
  const int rg = wave >> 1, cg = wave & 1;
  const int row0 = blockIdx.x * 128;

  if (tid < C_DIM) { s_sum[tid] = 0.f; s_ssum[tid] = 0.f; }

  // preload nbr indices for the block's 128 rows (coalesced), clamp OOB rows
  for (int i = tid; i < 128 * K_DIM; i += 256) {
    int r = i / K_DIM;
    int k = i - r * K_DIM;
    int rr = row0 + r; if (rr >= N) rr = N - 1;
    idx_lds[i] = nbr[(size_t)rr * K_DIM + k];
  }
  __syncthreads();

  const int gr = wave * 32 + (lane >> 2);   // gather row for c=0 (c=1: +16)
  const int gcol = (lane & 3) * 8;          // element offset within 32-ci row

  auto stage_a = [&](int gA, int gB, int q, int buf) {
    unsigned short* dst = Abuf + buf * 4096 + wave * 1024;   // wave-uniform
    async_copy16(xb + (size_t)gA * C_DIM + q * 32 + gcol, dst);
    async_copy16(xb + (size_t)gB * C_DIM + q * 32 + gcol, dst + 512);
  };
  auto stage_w = [&](int p, int buf) {
    const unsigned short* src = Wt + (size_t)p * 4096 + wave * 1024 + lane * 8;
    unsigned short* dst = Wbuf + buf * 4096 + wave * 1024;
    async_copy16(src, dst);
    async_copy16(src + 512, dst + 512);
  };

  f32x4 acc[4][4] = {};

  auto compute = [&](int buf) {
    const unsigned short* ab = Abuf + buf * 4096 + (rg * 64 + lr) * 32 + lg * 8;
    const unsigned short* wb = Wbuf + buf * 4096 + (cg * 64 + lr) * 32 + lg * 8;
    short8 a[4], b[4];
#pragma unroll
    for (int rt = 0; rt < 4; ++rt) a[rt] = *(const short8*)(ab + rt * 512);
#pragma unroll
    for (int ct = 0; ct < 4; ++ct) b[ct] = *(const short8*)(wb + ct * 512);
    __builtin_amdgcn_s_setprio(1);
#pragma unroll
    for (int rt = 0; rt < 4; ++rt)
#pragma unroll
      for (int ct = 0; ct < 4; ++ct)
        acc[rt][ct] = __builtin_amdgcn_mfma_f32_16x16x32_bf16(a[rt], b[ct], acc[rt][ct], 0, 0, 0);
    __builtin_amdgcn_s_setprio(0);
  };

  // ---- prologue: gi(k=0); stage phases 0,1,2 into bufs 0,1,2 ----
  int gA = idx_lds[gr * K_DIM];
  int gB = idx_lds[(gr + 16) * K_DIM];
  LGKM0();
  stage_a(gA, gB, 0, 0); stage_w(0, 0);
  stage_a(gA, gB, 1, 1); stage_w(1, 1);
  stage_a(gA, gB, 2, 2); stage_w(2, 2);
  VMCNT8();        // phase-0 tiles landed; 8 loads (ph 1,2) in flight
  BAR();

  // ---- main loop: 104 iters (p = base+u), stage p+3, compute p ----
  for (int base = 0; base < 104; base += 4) {
    const int k1 = (base >> 2) + 1;    // k for stages base+4..base+7
    int hA, hB;
    // u=0: stage s=base+3 (k=base/4, q=3, buf 3)
    stage_a(gA, gB, 3, 3); stage_w(base + 3, 3);
    hA = idx_lds[gr * K_DIM + k1];
    hB = idx_lds[(gr + 16) * K_DIM + k1];
    compute(0);
    LGKM0(); VMCNT8(); BAR();
    // u=1: stage s=base+4 (k1, q=0, buf 0)
    stage_a(hA, hB, 0, 0); stage_w(base + 4, 0);
    compute(1);
    LGKM0(); VMCNT8(); BAR();
    // u=2: stage s=base+5 (k1, q=1, buf 1)
    stage_a(hA, hB, 1, 1); stage_w(base + 5, 1);
    compute(2);
    LGKM0(); VMCNT8(); BAR();
    // u=3: stage s=base+6 (k1, q=2, buf 2)
    stage_a(hA, hB, 2, 2); stage_w(base + 6, 2);
    compute(3);
    LGKM0(); VMCNT8(); BAR();
    gA = hA; gB = hB;
  }

  // ---- tail: p = 104..107 ----
  stage_a(gA, gB, 3, 3); stage_w(107, 3);   // stage phase 107 (k=26, q=3)
  compute(0);
  LGKM0(); VMCNT8(); BAR();
  compute(1);
  LGKM0(); VMCNT4(); BAR();
  compute(2);
  LGKM0(); VMCNT0(); BAR();
  compute(3);

  // ---- epilogue: acc -> LDS ctile -> coalesced stores; fused BN stats ----
  __syncthreads();
  float* ctile = (float*)smem;   // 128x128 f32 = 64 KB (Abuf+Wbuf regions)
  float ps[4] = {0.f, 0.f, 0.f, 0.f}, pss[4] = {0.f, 0.f, 0.f, 0.f};
#pragma unroll
  for (int rt = 0; rt < 4; ++rt) {
#pragma unroll
    for (int j = 0; j < 4; ++j) {
      int lrow = rg * 64 + rt * 16 + lg * 4 + j;
      bool ok = (row0 + lrow) < N;
#pragma unroll
      for (int ct = 0; ct < 4; ++ct) {
        float v = acc[rt][ct][j];
        ctile[lrow * C_DIM + cg * 64 + ct * 16 + lr] = v;
        if (ok) { ps[ct] += v; pss[ct] += v * v; }
      }
    }
  }
#pragma unroll
  for (int ct = 0; ct < 4; ++ct) {
    ps[ct]  += __shfl_xor(ps[ct], 16, 64);
    ps[ct]  += __shfl_xor(ps[ct], 32, 64);
    pss[ct] += __shfl_xor(pss[ct], 16, 64);
    pss[ct] += __shfl_xor(pss[ct], 32, 64);
    if (lg == 0) {
      int col = cg * 64 + ct * 16 + lr;
      atomicAdd(&s_sum[col], ps[ct]);
      atomicAdd(&s_ssum[col], pss[ct]);
    }
  }
  __syncthreads();
  if (tid < C_DIM) {
    atomicAdd(&stats[tid], s_sum[tid]);
    atomicAdd(&stats[C_DIM + tid], s_ssum[tid]);
  }
  // coalesced writeback: 4096 f32x4 chunks, 16 per thread
  for (int i = tid; i < 4096; i += 256) {
    int row = i >> 5;
    int c4 = i & 31;
    int grow = row0 + row;
    if (grow >= N) continue;
    f32x4 v = ((const f32x4*)ctile)[i];
    if (OUT_IS_F32) {
      ((f32x4*)out_v)[(size_t)grow * 32 + c4] = v;
    } else {
      ushort4v u;
#pragma unroll
      for (int j = 0; j < 4; ++j) u[j] = f2bf(v[j]);
      ((ushort4v*)out_v)[(size_t)grow * 32 + c4] = u;
    }
  }
}

// ---- stats -> scale/shift ----
__global__ void finalize_kernel(const float* __restrict__ stats,
                                const float* __restrict__ g,
                                const float* __restrict__ b,
                                float* __restrict__ sshift, float invN) {
  int c = threadIdx.x;  // blockDim = 128
  float mean = stats[c] * invN;
  float var = stats[128 + c] * invN - mean * mean;
  float sc = g[c] * rsqrtf(var + 1e-5f);
  sshift[c] = sc;
  sshift[128 + c] = b[c] - mean * sc;
}

// ---- y1 <- relu(bn(y1)) in place, bf16 ----
__global__ __launch_bounds__(256) void apply_kernel(
    unsigned short* __restrict__ y, const float* __restrict__ ss, int total8) {
  int i = blockIdx.x * 256 + threadIdx.x;
  if (i >= total8) return;
  int cb = (i * 8) & 127;
  short8 u = ((short8*)y)[i];
#pragma unroll
  for (int j = 0; j < 8; ++j) {
    float f = bf2f((unsigned short)u[j]) * ss[cb + j] + ss[128 + cb + j];
    u[j] = (short)f2bf(fmaxf(f, 0.f));
  }
  ((short8*)y)[i] = u;
}

// ---- out <- relu(bn(y2) + x) in place (f32) ----
__global__ __launch_bounds__(256) void final_kernel(
    float* __restrict__ y2, const float* __restrict__ x,
    const float* __restrict__ ss, int total4) {
  int i = blockIdx.x * 256 + threadIdx.x;
  if (i >= total4) return;
  int cb = (i * 4) & 127;
  f32x4 v = ((const f32x4*)y2)[i];
  f32x4 xv = ((const f32x4*)x)[i];
#pragma unroll
  for (int j = 0; j < 4; ++j)
    v[j] = fmaxf(v[j] * ss[cb + j] + ss[128 + cb + j] + xv[j], 0.f);
  ((f32x4*)y2)[i] = v;
}

extern "C" void kernel_launch(void* const* d_in, const int* in_sizes, int n_in,
                              void* d_out, int out_size, void* d_ws, size_t ws_size,
                              hipStream_t stream) {
  const float* x  = (const float*)d_in[0];
  const int* nbr  = (const int*)d_in[1];
  const float* W1 = (const float*)d_in[2];
  const float* g1 = (const float*)d_in[3];
  const float* b1 = (const float*)d_in[4];
  const float* W2 = (const float*)d_in[5];
  const float* g2 = (const float*)d_in[6];
  const float* b2 = (const float*)d_in[7];
  float* out = (float*)d_out;

  const int N = in_sizes[0] / C_DIM;
  const int totalW = K_DIM * C_DIM * C_DIM;
  const int SMEM_BYTES = 65536 + 13824 + 1024;   // 80384 -> 2 blocks/CU

  char* ws = (char*)d_ws;
  size_t off = 0;
  auto alloc = [&](size_t bytes) {
    void* p = ws + off;
    off = (off + bytes + 255) & ~(size_t)255;
    return p;
  };
  unsigned short* Wt1 = (unsigned short*)alloc((size_t)totalW * 2);
  unsigned short* Wt2 = (unsigned short*)alloc((size_t)totalW * 2);
  float* stats = (float*)alloc(512 * 4);   // [0:256) conv1, [256:512) conv2
  float* ss1   = (float*)alloc(256 * 4);
  float* ss2   = (float*)alloc(256 * 4);
  unsigned short* y1 = (unsigned short*)alloc((size_t)N * C_DIM * 2);
  unsigned short* xb_ws = (unsigned short*)alloc((size_t)N * C_DIM * 2);
  // fall back to d_out's storage for the bf16 x copy if ws is too small
  unsigned short* xb = (off <= ws_size) ? xb_ws : (unsigned short*)d_out;

  (void)hipFuncSetAttribute((const void*)conv_kernel<0>,
      hipFuncAttributeMaxDynamicSharedMemorySize, SMEM_BYTES);
  (void)hipFuncSetAttribute((const void*)conv_kernel<1>,
      hipFuncAttributeMaxDynamicSharedMemorySize, SMEM_BYTES);

  const int nblk = (N + 127) / 128;
  const float invN = 1.0f / (float)N;

  prep_kernel<<<(totalW + 255) / 256, 256, 0, stream>>>(W1, W2, Wt1, Wt2, stats, 512);

  {
    int t4 = N * C_DIM / 4;
    cvt_x_kernel<<<(t4 + 255) / 256, 256, 0, stream>>>(x, xb, t4);
  }

  conv_kernel<0><<<nblk, 256, SMEM_BYTES, stream>>>(xb, nbr, Wt1, y1, stats, N);
  finalize_kernel<<<1, 128, 0, stream>>>(stats, g1, b1, ss1, invN);

  {
    int t8 = N * C_DIM / 8;
    apply_kernel<<<(t8 + 255) / 256, 256, 0, stream>>>(y1, ss1, t8);
  }

  conv_kernel<1><<<nblk, 256, SMEM_BYTES, stream>>>(y1, nbr, Wt2, out, stats + 256, N);
  finalize_kernel<<<1, 128, 0, stream>>>(stats + 256, g2, b2, ss2, invN);

  {
    int t4 = N * C_DIM / 4;
    final_kernel<<<(t4 + 255) / 256, 256, 0, stream>>>(out, x, ss2, t4);
  }
}